// Round 1
// baseline (396.231 us; speedup 1.0000x reference)
//
#include <hip/hip_runtime.h>

// ---------- types ----------
typedef __attribute__((ext_vector_type(8))) __bf16 bf16x8;   // MFMA A/B frag (4 VGPR)
typedef __attribute__((ext_vector_type(4))) float  f32x4;    // MFMA C/D frag
typedef __attribute__((ext_vector_type(4))) unsigned short us4;

__device__ __forceinline__ unsigned short f2bf(float f) {
    unsigned u = __float_as_uint(f);
    u += 0x7fffu + ((u >> 16) & 1u);          // RNE, inputs are finite
    return (unsigned short)(u >> 16);
}

__device__ __forceinline__ void gload_lds16(const void* g, void* l) {
    __builtin_amdgcn_global_load_lds((const __attribute__((address_space(1))) void*)g,
                                     (__attribute__((address_space(3))) void*)l, 16, 0, 0);
}

// ---------- fp32 -> bf16 ----------
__global__ __launch_bounds__(256) void f32_to_bf16_k(const float* __restrict__ in,
                                                     unsigned short* __restrict__ out, int n) {
    int i = (blockIdx.x * 256 + threadIdx.x) * 4;
    if (i + 3 < n) {
        float4 v = *(const float4*)(in + i);
        us4 o;
        o.x = f2bf(v.x); o.y = f2bf(v.y); o.z = f2bf(v.z); o.w = f2bf(v.w);
        *(us4*)(out + i) = o;
    }
}

// ---------- GEMM: C[M,N] = A[M,K] * B[N,K]^T + bias, A/B bf16 ----------
// 128x128 tile, BK=32, 256 threads = 4 waves in 2x2, each wave 64x64 (4x4 frags of 16x16x32).
// LDS layout [kc][row][8]: linear for global_load_lds in thread order, conflict-free ds_read_b128.
template <int OUTF>   // 0: bf16 out, 1: f32 out
__global__ __launch_bounds__(256, 2) void gemm_bt(const unsigned short* __restrict__ A,
                                                  const unsigned short* __restrict__ B,
                                                  const float* __restrict__ bias,
                                                  void* __restrict__ Cv,
                                                  int M, int N, int K) {
    __shared__ unsigned short As[4 * 128 * 8];
    __shared__ unsigned short Bs[4 * 128 * 8];
    const int t = threadIdx.x;
    const int lane = t & 63;
    const int w = t >> 6;
    const int wr = w >> 1, wc = w & 1;
    const int lhi = lane >> 4, llo = lane & 15;
    const int bm = blockIdx.y, bn = blockIdx.x;

    f32x4 acc[4][4] = {};

    const unsigned short* Ag = A + (size_t)(bm * 128) * K;
    const unsigned short* Bg = B + (size_t)(bn * 128) * K;

    const int r0 = t & 127, kc0 = t >> 7;              // staging iter 0: idx = t
    const int r1 = (256 + t) & 127, kc1 = (256 + t) >> 7;  // iter 1: idx = 256+t
    const int wbase = (t & ~63) * 8;                   // wave-uniform LDS elem offset

    const int KT = K >> 5;
    for (int kt = 0; kt < KT; ++kt) {
        const int k0 = kt * 32;
        gload_lds16(Ag + (size_t)r0 * K + k0 + kc0 * 8, As + wbase);
        gload_lds16(Ag + (size_t)r1 * K + k0 + kc1 * 8, As + 2048 + wbase);
        gload_lds16(Bg + (size_t)r0 * K + k0 + kc0 * 8, Bs + wbase);
        gload_lds16(Bg + (size_t)r1 * K + k0 + kc1 * 8, Bs + 2048 + wbase);
        __syncthreads();   // drains vmcnt (global_load_lds) + barrier

        bf16x8 af[4], bfr[4];
#pragma unroll
        for (int mi = 0; mi < 4; ++mi)
            af[mi] = *(const bf16x8*)(As + lhi * 1024 + (wr * 64 + mi * 16 + llo) * 8);
#pragma unroll
        for (int ni = 0; ni < 4; ++ni)
            bfr[ni] = *(const bf16x8*)(Bs + lhi * 1024 + (wc * 64 + ni * 16 + llo) * 8);
#pragma unroll
        for (int mi = 0; mi < 4; ++mi)
#pragma unroll
            for (int ni = 0; ni < 4; ++ni)
                acc[mi][ni] = __builtin_amdgcn_mfma_f32_16x16x32_bf16(af[mi], bfr[ni], acc[mi][ni], 0, 0, 0);
        __syncthreads();   // all waves done reading before next stage
    }

    // epilogue: C/D layout col = lane&15, row = (lane>>4)*4 + r
    const int rowb = bm * 128 + wr * 64;
    const int colb = bn * 128 + wc * 64;
#pragma unroll
    for (int mi = 0; mi < 4; ++mi) {
#pragma unroll
        for (int ni = 0; ni < 4; ++ni) {
            const int col = colb + ni * 16 + llo;
            const float bv = bias[col];
#pragma unroll
            for (int r = 0; r < 4; ++r) {
                const int row = rowb + mi * 16 + lhi * 4 + r;
                const float v = acc[mi][ni][r] + bv;
                if (OUTF == 0) ((unsigned short*)Cv)[(size_t)row * N + col] = f2bf(v);
                else           ((float*)Cv)[(size_t)row * N + col] = v;
            }
        }
    }
}

// ---------- flash attention ----------
// qkv bf16 [8192][3072] with columns: k=0:1024, q=1024:2048, v=2048:3072 (reference chunk order!).
// grid (32 q-tiles, 64 b*h); block 256 = 4 waves, each wave owns 16 q-rows. K-tiles of 64 keys.
__global__ __launch_bounds__(256, 2) void attn_k(const unsigned short* __restrict__ qkv,
                                                 unsigned short* __restrict__ score) {
    __shared__ unsigned short Ks[8 * 64 * 8];   // [kc(d/8)][key][8]  8KB
    __shared__ unsigned short Vt[64 * 88];      // [d][key], row stride 88 (16B aligned, ~2-way banks)
    __shared__ unsigned short Pl[4][16 * 88];   // per-wave P scratch [qrow][key]

    const int t = threadIdx.x;
    const int lane = t & 63;
    const int w = t >> 6;
    const int lhi = lane >> 4, llo = lane & 15;
    const int qt = blockIdx.x, bh = blockIdx.y;
    const int b = bh >> 4, h = bh & 15;
    const int q0 = qt * 64;

    // Q fragments for this wave's 16 rows: A(m,k) lane m=llo, k=lhi*8+e (+32 for ds=1)
    bf16x8 qf[2];
    {
        const size_t row = (size_t)(b * 2048 + q0 + w * 16 + llo);
        const unsigned short* qp = qkv + row * 3072 + 1024 + h * 64 + lhi * 8;
        qf[0] = *(const bf16x8*)(qp);
        qf[1] = *(const bf16x8*)(qp + 32);
    }

    f32x4 oacc[4] = {};
    float m_[4], l_[4];
#pragma unroll
    for (int r = 0; r < 4; ++r) { m_[r] = -1e30f; l_[r] = 0.f; }

    for (int kt = 0; kt < 32; ++kt) {
        const int key0 = kt * 64;
        // stage K tile (64 keys x 64 d) via global_load_lds, chunked layout
        {
            int idx = t, key = idx & 63, kc = idx >> 6;
            gload_lds16(qkv + (size_t)(b * 2048 + key0 + key) * 3072 + h * 64 + kc * 8,
                        Ks + (t & ~63) * 8);
            idx = 256 + t; key = idx & 63; kc = idx >> 6;
            gload_lds16(qkv + (size_t)(b * 2048 + key0 + key) * 3072 + h * 64 + kc * 8,
                        Ks + 2048 + (t & ~63) * 8);
        }
        // stage V transposed (register round-trip)
#pragma unroll
        for (int it = 0; it < 2; ++it) {
            const int idx = it * 256 + t;
            const int key = idx & 63, dc = idx >> 6;
            bf16x8 v = *(const bf16x8*)(qkv + (size_t)(b * 2048 + key0 + key) * 3072 + 2048 + h * 64 + dc * 8);
            union { bf16x8 v8; unsigned short u[8]; } cv; cv.v8 = v;
#pragma unroll
            for (int j = 0; j < 8; ++j) Vt[(dc * 8 + j) * 88 + key] = cv.u[j];
        }
        __syncthreads();

        // S = Q K^T (16 x 64), 4 n-frags x 2 k-steps
        f32x4 sa[4] = {};
#pragma unroll
        for (int ds = 0; ds < 2; ++ds) {
#pragma unroll
            for (int nf = 0; nf < 4; ++nf) {
                bf16x8 kb = *(const bf16x8*)(Ks + (ds * 4 + lhi) * 512 + (nf * 16 + llo) * 8);
                sa[nf] = __builtin_amdgcn_mfma_f32_16x16x32_bf16(qf[ds], kb, sa[nf], 0, 0, 0);
            }
        }
#pragma unroll
        for (int nf = 0; nf < 4; ++nf)
#pragma unroll
            for (int r = 0; r < 4; ++r) sa[nf][r] *= 0.125f;

        // online softmax; row r of this lane's group lives in 16 lanes (cols)
        float corr[4];
#pragma unroll
        for (int r = 0; r < 4; ++r) {
            float pm = fmaxf(fmaxf(sa[0][r], sa[1][r]), fmaxf(sa[2][r], sa[3][r]));
#pragma unroll
            for (int off = 1; off < 16; off <<= 1) pm = fmaxf(pm, __shfl_xor(pm, off, 64));
            const float mn = fmaxf(m_[r], pm);
            corr[r] = __expf(m_[r] - mn);
            float rs = 0.f;
#pragma unroll
            for (int nf = 0; nf < 4; ++nf) {
                const float p = __expf(sa[nf][r] - mn);
                sa[nf][r] = p;
                rs += p;
            }
#pragma unroll
            for (int off = 1; off < 16; off <<= 1) rs += __shfl_xor(rs, off, 64);
            l_[r] = l_[r] * corr[r] + rs;
            m_[r] = mn;
#pragma unroll
            for (int nf = 0; nf < 4; ++nf) oacc[nf][r] *= corr[r];
        }

        // P -> LDS (C-layout scatter), then read back as A-frags
        unsigned short* pw = Pl[w];
#pragma unroll
        for (int nf = 0; nf < 4; ++nf)
#pragma unroll
            for (int r = 0; r < 4; ++r)
                pw[(lhi * 4 + r) * 88 + nf * 16 + llo] = f2bf(sa[nf][r]);

        // O += P V  (16 x 64, K = 64 keys in 2 steps)
#pragma unroll
        for (int ks = 0; ks < 2; ++ks) {
            bf16x8 pa = *(const bf16x8*)(pw + llo * 88 + ks * 32 + lhi * 8);
#pragma unroll
            for (int nf = 0; nf < 4; ++nf) {
                bf16x8 vb = *(const bf16x8*)(Vt + (nf * 16 + llo) * 88 + ks * 32 + lhi * 8);
                oacc[nf] = __builtin_amdgcn_mfma_f32_16x16x32_bf16(pa, vb, oacc[nf], 0, 0, 0);
            }
        }
        __syncthreads();
    }

    // normalize + store score[b,s,h*64+d] bf16
#pragma unroll
    for (int nf = 0; nf < 4; ++nf) {
        const int col = h * 64 + nf * 16 + llo;
#pragma unroll
        for (int r = 0; r < 4; ++r) {
            const int row = b * 2048 + q0 + w * 16 + lhi * 4 + r;
            score[(size_t)row * 1024 + col] = f2bf(oacc[nf][r] / l_[r]);
        }
    }
}

// ---------- launch ----------
extern "C" void kernel_launch(void* const* d_in, const int* in_sizes, int n_in,
                              void* d_out, int out_size, void* d_ws, size_t ws_size,
                              hipStream_t stream) {
    const float* x  = (const float*)d_in[0];   // [4,2048,1024]
    const float* w1 = (const float*)d_in[1];   // [3072,1024]
    const float* b1 = (const float*)d_in[2];   // [3072]
    const float* w2 = (const float*)d_in[3];   // [1024,1024]
    const float* b2 = (const float*)d_in[4];   // [1024]
    float* out = (float*)d_out;                // [4,2048,1024] fp32

    char* ws = (char*)d_ws;
    unsigned short* qkv   = (unsigned short*)ws;                                      // 48 MB
    unsigned short* xbf   = (unsigned short*)(ws + 50331648);                         // 16 MB
    unsigned short* w1bf  = (unsigned short*)(ws + 50331648 + 16777216);              // 6 MB
    unsigned short* w2bf  = (unsigned short*)(ws + 50331648 + 16777216 + 6291456);    // 2 MB
    unsigned short* score = xbf;  // x is dead after GEMM1; alias (stream-ordered)

    f32_to_bf16_k<<<dim3(8388608 / 1024), dim3(256), 0, stream>>>(x,  xbf,  8388608);
    f32_to_bf16_k<<<dim3(3145728 / 1024), dim3(256), 0, stream>>>(w1, w1bf, 3145728);
    f32_to_bf16_k<<<dim3(1048576 / 1024), dim3(256), 0, stream>>>(w2, w2bf, 1048576);

    gemm_bt<0><<<dim3(24, 64), dim3(256), 0, stream>>>(xbf, w1bf, b1, (void*)qkv, 8192, 3072, 1024);
    attn_k<<<dim3(32, 64), dim3(256), 0, stream>>>(qkv, score);
    gemm_bt<1><<<dim3(8, 64), dim3(256), 0, stream>>>(score, w2bf, b2, (void*)out, 8192, 1024, 1024);
}

// Round 2
// 321.536 us; speedup vs baseline: 1.2323x; 1.2323x over previous
//
#include <hip/hip_runtime.h>

// ---------- types ----------
typedef __attribute__((ext_vector_type(8))) __bf16 bf16x8;   // MFMA A/B frag (4 VGPR)
typedef __attribute__((ext_vector_type(4))) float  f32x4;    // MFMA C/D frag
typedef __attribute__((ext_vector_type(4))) unsigned short us4;

#define QK_SCALE 0.180336880111112f   // 0.125 * log2(e): softmax runs in exp2 domain

__device__ __forceinline__ unsigned short f2bf(float f) {
    unsigned u = __float_as_uint(f);
    u += 0x7fffu + ((u >> 16) & 1u);          // RNE, inputs are finite
    return (unsigned short)(u >> 16);
}

__device__ __forceinline__ void gload_lds16(const void* g, void* l) {
    __builtin_amdgcn_global_load_lds((const __attribute__((address_space(1))) void*)g,
                                     (__attribute__((address_space(3))) void*)l, 16, 0, 0);
}

template <int CTRL>
__device__ __forceinline__ float dpp_mov(float x) {
    return __int_as_float(__builtin_amdgcn_update_dpp(0, __float_as_int(x), CTRL, 0xf, 0xf, true));
}
// reductions across the 16-lane row group (row_ror:1/2/4/8) — VALU, no DS pipe
__device__ __forceinline__ float rmax16(float v) {
    v = fmaxf(v, dpp_mov<0x121>(v));
    v = fmaxf(v, dpp_mov<0x122>(v));
    v = fmaxf(v, dpp_mov<0x124>(v));
    v = fmaxf(v, dpp_mov<0x128>(v));
    return v;
}
__device__ __forceinline__ float rsum16(float v) {
    v += dpp_mov<0x121>(v);
    v += dpp_mov<0x122>(v);
    v += dpp_mov<0x124>(v);
    v += dpp_mov<0x128>(v);
    return v;
}

// ---------- fp32 -> bf16 ----------
__global__ __launch_bounds__(256) void f32_to_bf16_k(const float* __restrict__ in,
                                                     unsigned short* __restrict__ out, int n) {
    int i = (blockIdx.x * 256 + threadIdx.x) * 4;
    if (i + 3 < n) {
        float4 v = *(const float4*)(in + i);
        us4 o;
        o.x = f2bf(v.x); o.y = f2bf(v.y); o.z = f2bf(v.z); o.w = f2bf(v.w);
        *(us4*)(out + i) = o;
    }
}

// w1 conversion with QK_SCALE folded into the q-chunk rows [1024,2048)
__global__ __launch_bounds__(256) void cvt_w1_k(const float* __restrict__ in,
                                                unsigned short* __restrict__ out) {
    int i = (blockIdx.x * 256 + threadIdx.x) * 4;   // n = 3145728, K=1024 per row
    float4 v = *(const float4*)(in + i);
    const int row = i >> 10;
    const float s = (row >= 1024 && row < 2048) ? QK_SCALE : 1.0f;
    us4 o;
    o.x = f2bf(v.x * s); o.y = f2bf(v.y * s); o.z = f2bf(v.z * s); o.w = f2bf(v.w * s);
    *(us4*)(out + i) = o;
}

// ---------- GEMM: C[M,N] = A[M,K] * B[N,K]^T + bias ----------
// 128x128 tile, BK=32, 4 waves in 2x2, each wave 64x64 (4x4 frags of 16x16x32).
template <int OUTF, int QS>   // OUTF: 0 bf16 out, 1 f32 out. QS: scale bias cols [1024,2048)
__global__ __launch_bounds__(256, 2) void gemm_bt(const unsigned short* __restrict__ A,
                                                  const unsigned short* __restrict__ B,
                                                  const float* __restrict__ bias,
                                                  void* __restrict__ Cv,
                                                  int M, int N, int K) {
    __shared__ unsigned short As[4 * 128 * 8];
    __shared__ unsigned short Bs[4 * 128 * 8];
    const int t = threadIdx.x;
    const int lane = t & 63;
    const int w = t >> 6;
    const int wr = w >> 1, wc = w & 1;
    const int lhi = lane >> 4, llo = lane & 15;
    const int bm = blockIdx.y, bn = blockIdx.x;

    f32x4 acc[4][4] = {};

    const unsigned short* Ag = A + (size_t)(bm * 128) * K;
    const unsigned short* Bg = B + (size_t)(bn * 128) * K;

    const int r0 = t & 127, kc0 = t >> 7;
    const int r1 = (256 + t) & 127, kc1 = (256 + t) >> 7;
    const int wbase = (t & ~63) * 8;

    const int KT = K >> 5;
    for (int kt = 0; kt < KT; ++kt) {
        const int k0 = kt * 32;
        gload_lds16(Ag + (size_t)r0 * K + k0 + kc0 * 8, As + wbase);
        gload_lds16(Ag + (size_t)r1 * K + k0 + kc1 * 8, As + 2048 + wbase);
        gload_lds16(Bg + (size_t)r0 * K + k0 + kc0 * 8, Bs + wbase);
        gload_lds16(Bg + (size_t)r1 * K + k0 + kc1 * 8, Bs + 2048 + wbase);
        __syncthreads();

        bf16x8 af[4], bfr[4];
#pragma unroll
        for (int mi = 0; mi < 4; ++mi)
            af[mi] = *(const bf16x8*)(As + lhi * 1024 + (wr * 64 + mi * 16 + llo) * 8);
#pragma unroll
        for (int ni = 0; ni < 4; ++ni)
            bfr[ni] = *(const bf16x8*)(Bs + lhi * 1024 + (wc * 64 + ni * 16 + llo) * 8);
#pragma unroll
        for (int mi = 0; mi < 4; ++mi)
#pragma unroll
            for (int ni = 0; ni < 4; ++ni)
                acc[mi][ni] = __builtin_amdgcn_mfma_f32_16x16x32_bf16(af[mi], bfr[ni], acc[mi][ni], 0, 0, 0);
        __syncthreads();
    }

    const int rowb = bm * 128 + wr * 64;
    const int colb = bn * 128 + wc * 64;
#pragma unroll
    for (int mi = 0; mi < 4; ++mi) {
#pragma unroll
        for (int ni = 0; ni < 4; ++ni) {
            const int col = colb + ni * 16 + llo;
            float bv = bias[col];
            if (QS) bv = (col >= 1024 && col < 2048) ? bv * QK_SCALE : bv;
#pragma unroll
            for (int r = 0; r < 4; ++r) {
                const int row = rowb + mi * 16 + lhi * 4 + r;
                const float v = acc[mi][ni][r] + bv;
                if (OUTF == 0) ((unsigned short*)Cv)[(size_t)row * N + col] = f2bf(v);
                else           ((float*)Cv)[(size_t)row * N + col] = v;
            }
        }
    }
}

// ---------- flash attention ----------
// qkv bf16 [8192][3072], chunks (k,q,v): k=0:1024, q=1024:2048 (pre-scaled by QK_SCALE), v=2048:3072.
// grid (16 q-tiles, 64 b*h); block 256 = 4 waves, each wave owns 32 q-rows. K-tiles of 64 keys.
// Pipelined: K(t+1) via global_load_lds dbuf, V(t+1) in regs; raw s_barrier (no vmcnt drain).
__global__ __launch_bounds__(256) void attn_k(const unsigned short* __restrict__ qkv,
                                              unsigned short* __restrict__ score) {
    __shared__ unsigned short Ks[2][4096];      // [buf][kc8][key64][8]  2x8KB
    __shared__ unsigned short Vt[64 * 88];      // [d][key] stride 88
    __shared__ unsigned short Pl[4][16 * 88];   // per-wave P scratch [qrow16][key-rotated]

    const int t = threadIdx.x;
    const int lane = t & 63;
    const int w = t >> 6;
    const int lhi = lane >> 4, llo = lane & 15;
    const int b = blockIdx.y >> 4, h = blockIdx.y & 15;
    const int q0 = blockIdx.x * 128;

    const unsigned short* kvb = qkv + (size_t)b * 2048 * 3072 + h * 64;

    // Q fragments: rows q0 + w*32 + mf*16 + llo, k = ds*32 + lhi*8 + e
    bf16x8 qf[2][2];
#pragma unroll
    for (int mf = 0; mf < 2; ++mf) {
        const unsigned short* qp = qkv + (size_t)(b * 2048 + q0 + w * 32 + mf * 16 + llo) * 3072
                                   + 1024 + h * 64 + lhi * 8;
        qf[mf][0] = *(const bf16x8*)qp;
        qf[mf][1] = *(const bf16x8*)(qp + 32);
    }

    f32x4 oacc[2][4] = {};
    float m_[2][4], l_[2][4];
#pragma unroll
    for (int mf = 0; mf < 2; ++mf)
#pragma unroll
        for (int r = 0; r < 4; ++r) { m_[mf][r] = -1e30f; l_[mf][r] = 0.f; }

    const int vp = t & 31, vdc = t >> 5;        // V staging: key-pair vp, d-chunk vdc
    bf16x8 vr0, vr1;

    auto issueK = [&](int kt, int buf) {
        const unsigned short* g = kvb + (size_t)(kt * 64 + (t & 63)) * 3072 + (t >> 6) * 8;
        gload_lds16(g,      &Ks[buf][(t & ~63) * 8]);          // kc = w
        gload_lds16(g + 32, &Ks[buf][2048 + (t & ~63) * 8]);   // kc = w+4
    };
    auto issueV = [&](int kt) {
        const unsigned short* g = kvb + 2048 + (size_t)(kt * 64 + 2 * vp) * 3072 + vdc * 8;
        vr0 = *(const bf16x8*)g;
        vr1 = *(const bf16x8*)(g + 3072);
    };
    auto writeVt = [&]() {
        union { bf16x8 v; unsigned short u[8]; } a, c;
        a.v = vr0; c.v = vr1;
        unsigned int* V32 = (unsigned int*)Vt;
#pragma unroll
        for (int j = 0; j < 8; ++j)
            V32[(vdc * 8 + j) * 44 + vp] = (unsigned int)a.u[j] | ((unsigned int)c.u[j] << 16);
    };

    issueK(0, 0);
    __builtin_amdgcn_sched_barrier(0);   // pin: K issue before V issue (in-order vmcnt trick)
    issueV(0);

    for (int kt = 0; kt < 32; ++kt) {
        const int cur = kt & 1;
        if (kt < 31) issueK(kt + 1, cur ^ 1);
        __builtin_amdgcn_sched_barrier(0);           // pin K(t+1) before the vr(t) use below
        writeVt();                                   // compiler's vmcnt wait on vr(t) => K(t) DMA landed
        if (kt < 31) issueV(kt + 1);
        asm volatile("s_waitcnt lgkmcnt(0)" ::: "memory");   // Vt writes visible
        __builtin_amdgcn_sched_barrier(0);
        __builtin_amdgcn_s_barrier();                // NO vmcnt drain: K(t+1)/V(t+1) stay in flight
        __builtin_amdgcn_sched_barrier(0);

        // ---- S = Q K^T (32 x 64 per wave) ----
        f32x4 sa[2][4] = {};
#pragma unroll
        for (int ds = 0; ds < 2; ++ds) {
#pragma unroll
            for (int nf = 0; nf < 4; ++nf) {
                bf16x8 kb = *(const bf16x8*)(&Ks[cur][(ds * 4 + lhi) * 512 + (nf * 16 + llo) * 8]);
                sa[0][nf] = __builtin_amdgcn_mfma_f32_16x16x32_bf16(qf[0][ds], kb, sa[0][nf], 0, 0, 0);
                sa[1][nf] = __builtin_amdgcn_mfma_f32_16x16x32_bf16(qf[1][ds], kb, sa[1][nf], 0, 0, 0);
            }
        }

        // ---- online softmax (exp2 domain; lane holds P[q=lhi*4+r][key=nf*16+llo]) ----
        bf16x8 pa[2][2];
        unsigned short* pw = Pl[w];
#pragma unroll
        for (int mf = 0; mf < 2; ++mf) {
#pragma unroll
            for (int r = 0; r < 4; ++r) {
                float pm = fmaxf(fmaxf(sa[mf][0][r], sa[mf][1][r]), fmaxf(sa[mf][2][r], sa[mf][3][r]));
                pm = rmax16(pm);
                const float mn = fmaxf(m_[mf][r], pm);
                const float c = __builtin_amdgcn_exp2f(m_[mf][r] - mn);
                m_[mf][r] = mn;
                const float p0 = __builtin_amdgcn_exp2f(sa[mf][0][r] - mn);
                const float p1 = __builtin_amdgcn_exp2f(sa[mf][1][r] - mn);
                const float p2 = __builtin_amdgcn_exp2f(sa[mf][2][r] - mn);
                const float p3 = __builtin_amdgcn_exp2f(sa[mf][3][r] - mn);
                sa[mf][0][r] = p0; sa[mf][1][r] = p1; sa[mf][2][r] = p2; sa[mf][3][r] = p3;
                l_[mf][r] = l_[mf][r] * c + (p0 + p1 + p2 + p3);   // per-lane partial; reduced at end
#pragma unroll
                for (int nf = 0; nf < 4; ++nf) oacc[mf][nf][r] *= c;
            }
            // P scatter, key-rotated by 16*(row>>2): conflict-free, preserves 8-key read contiguity
#pragma unroll
            for (int nf = 0; nf < 4; ++nf) {
                const int pc = (nf * 16 + llo + (lhi << 4)) & 63;
#pragma unroll
                for (int r = 0; r < 4; ++r)
                    pw[(lhi * 4 + r) * 88 + pc] = f2bf(sa[mf][nf][r]);
            }
            const int xr = (llo & 12) << 2;   // 16*((row=llo)>>2)
            pa[mf][0] = *(const bf16x8*)(pw + llo * 88 + ((lhi * 8 + xr) & 63));
            pa[mf][1] = *(const bf16x8*)(pw + llo * 88 + ((32 + lhi * 8 + xr) & 63));
        }

        // ---- O += P V ----
#pragma unroll
        for (int ks = 0; ks < 2; ++ks) {
#pragma unroll
            for (int nf = 0; nf < 4; ++nf) {
                bf16x8 vb = *(const bf16x8*)(Vt + (nf * 16 + llo) * 88 + ks * 32 + lhi * 8);
                oacc[0][nf] = __builtin_amdgcn_mfma_f32_16x16x32_bf16(pa[0][ks], vb, oacc[0][nf], 0, 0, 0);
                oacc[1][nf] = __builtin_amdgcn_mfma_f32_16x16x32_bf16(pa[1][ks], vb, oacc[1][nf], 0, 0, 0);
            }
        }
        __builtin_amdgcn_sched_barrier(0);
        __builtin_amdgcn_s_barrier();                // readers done before next tile's writes
        __builtin_amdgcn_sched_barrier(0);
    }

    // ---- epilogue: reduce l across the 16-lane group once, normalize, store ----
#pragma unroll
    for (int mf = 0; mf < 2; ++mf) {
#pragma unroll
        for (int r = 0; r < 4; ++r) {
            const float L = rsum16(l_[mf][r]);
            const float rl = 1.0f / L;
            const int row = b * 2048 + q0 + w * 32 + mf * 16 + lhi * 4 + r;
#pragma unroll
            for (int nf = 0; nf < 4; ++nf)
                score[(size_t)row * 1024 + h * 64 + nf * 16 + llo] = f2bf(oacc[mf][nf][r] * rl);
        }
    }
}

// ---------- launch ----------
extern "C" void kernel_launch(void* const* d_in, const int* in_sizes, int n_in,
                              void* d_out, int out_size, void* d_ws, size_t ws_size,
                              hipStream_t stream) {
    const float* x  = (const float*)d_in[0];   // [4,2048,1024]
    const float* w1 = (const float*)d_in[1];   // [3072,1024]
    const float* b1 = (const float*)d_in[2];   // [3072]
    const float* w2 = (const float*)d_in[3];   // [1024,1024]
    const float* b2 = (const float*)d_in[4];   // [1024]
    float* out = (float*)d_out;                // [4,2048,1024] fp32

    char* ws = (char*)d_ws;
    unsigned short* qkv   = (unsigned short*)ws;                                      // 48 MB
    unsigned short* xbf   = (unsigned short*)(ws + 50331648);                         // 16 MB
    unsigned short* w1bf  = (unsigned short*)(ws + 50331648 + 16777216);              // 6 MB
    unsigned short* w2bf  = (unsigned short*)(ws + 50331648 + 16777216 + 6291456);    // 2 MB
    unsigned short* score = xbf;  // x dead after GEMM1; alias (stream-ordered)

    f32_to_bf16_k<<<dim3(8388608 / 1024), dim3(256), 0, stream>>>(x,  xbf,  8388608);
    cvt_w1_k<<<dim3(3145728 / 1024), dim3(256), 0, stream>>>(w1, w1bf);
    f32_to_bf16_k<<<dim3(1048576 / 1024), dim3(256), 0, stream>>>(w2, w2bf, 1048576);

    gemm_bt<0, 1><<<dim3(24, 64), dim3(256), 0, stream>>>(xbf, w1bf, b1, (void*)qkv, 8192, 3072, 1024);
    attn_k<<<dim3(16, 64), dim3(256), 0, stream>>>(qkv, score);
    gemm_bt<1, 0><<<dim3(8, 64), dim3(256), 0, stream>>>(score, w2bf, b2, (void*)out, 8192, 1024, 1024);
}